// Round 1
// baseline (302.547 us; speedup 1.0000x reference)
//
#include <hip/hip_runtime.h>
#include <math.h>

#define N_IN  128
#define N_HID 128
#define N_OUT 64

// ---------------- CSR build ----------------
__global__ void k_zero_int(int* __restrict__ p, int n) {
  int i = blockIdx.x * blockDim.x + threadIdx.x;
  if (i < n) p[i] = 0;
}

__global__ void k_hist(const int* __restrict__ dst, int E, int* __restrict__ cnt) {
  int stride = gridDim.x * blockDim.x;
  for (int i = blockIdx.x * blockDim.x + threadIdx.x; i < E; i += stride)
    atomicAdd(&cnt[dst[i]], 1);
}

#define SCAN_CHUNK 512

__global__ __launch_bounds__(SCAN_CHUNK) void k_block_sums(
    const int* __restrict__ cnt, int n, int* __restrict__ bsum) {
  __shared__ int s[SCAN_CHUNK];
  int i = blockIdx.x * SCAN_CHUNK + threadIdx.x;
  s[threadIdx.x] = (i < n) ? cnt[i] : 0;
  __syncthreads();
  for (int off = SCAN_CHUNK / 2; off > 0; off >>= 1) {
    if (threadIdx.x < off) s[threadIdx.x] += s[threadIdx.x + off];
    __syncthreads();
  }
  if (threadIdx.x == 0) bsum[blockIdx.x] = s[0];
}

__global__ void k_scan_bsums(int* __restrict__ bsum, int nb) {
  if (blockIdx.x == 0 && threadIdx.x == 0) {
    int acc = 0;
    for (int i = 0; i < nb; ++i) { int v = bsum[i]; bsum[i] = acc; acc += v; }
  }
}

__global__ __launch_bounds__(SCAN_CHUNK) void k_scan_final(
    const int* __restrict__ cnt, int n, const int* __restrict__ bsum,
    int* __restrict__ rowptr, float* __restrict__ dinv, int E) {
  __shared__ int s[SCAN_CHUNK];
  int i = blockIdx.x * SCAN_CHUNK + threadIdx.x;
  int v = (i < n) ? cnt[i] : 0;
  s[threadIdx.x] = v;
  __syncthreads();
  // Hillis-Steele inclusive scan
  for (int off = 1; off < SCAN_CHUNK; off <<= 1) {
    int t = (threadIdx.x >= off) ? s[threadIdx.x - off] : 0;
    __syncthreads();
    s[threadIdx.x] += t;
    __syncthreads();
  }
  if (i < n) {
    rowptr[i] = bsum[blockIdx.x] + s[threadIdx.x] - v;  // exclusive
    dinv[i] = rsqrtf((float)v + 1.0f);                   // +1 self loop
    if (i == n - 1) rowptr[n] = E;
  }
}

__global__ void k_fill(const int* __restrict__ src, const int* __restrict__ dst, int E,
                       const int* __restrict__ rowptr, int* __restrict__ fill,
                       int* __restrict__ csr) {
  int stride = gridDim.x * blockDim.x;
  for (int i = blockIdx.x * blockDim.x + threadIdx.x; i < E; i += stride) {
    int d = dst[i];
    int pos = rowptr[d] + atomicAdd(&fill[d], 1);
    csr[pos] = src[i];
  }
}

// ---------------- GEMM (+ dinv row scale): out[r][c] = dinv[r] * sum_k A[r][k]*W[k][c]
template <int N>
__global__ __launch_bounds__(256) void k_gemm_scale(
    const float* __restrict__ A,      // [M][128]
    const float* __restrict__ W,      // [128][N]
    const float* __restrict__ dinv,   // [M]
    float* __restrict__ out,          // [M][N]
    int M) {
  constexpr int K = 128, KC = 32, BM = 128;
  constexpr int TN = N / 16;  // 8 (N=128) or 4 (N=64)
  __shared__ __align__(16) float xsT[KC][BM + 4];  // [k][row], pad breaks write conflicts
  __shared__ __align__(16) float Ws[KC][N];

  int tid = threadIdx.x;
  int cx = tid & 15;        // col group
  int ry = tid >> 4;        // row group (0..15)
  int c0 = cx * TN;
  int r0 = ry * 8;
  int rowbase = blockIdx.x * BM;

  float acc[8][TN];
#pragma unroll
  for (int i = 0; i < 8; ++i)
#pragma unroll
    for (int j = 0; j < TN; ++j) acc[i][j] = 0.f;

  for (int kb = 0; kb < K; kb += KC) {
    // stage A tile transposed: xsT[k][row]
    {
      int kq = tid & 7;    // 8 float4 per 32-k chunk
      int rr = tid >> 3;   // 0..31
#pragma unroll
      for (int p = 0; p < 4; ++p) {
        int row = rr + p * 32;
        int grow = rowbase + row;
        float4 v = make_float4(0.f, 0.f, 0.f, 0.f);
        if (grow < M)
          v = *reinterpret_cast<const float4*>(&A[(size_t)grow * K + kb + kq * 4]);
        xsT[kq * 4 + 0][row] = v.x;
        xsT[kq * 4 + 1][row] = v.y;
        xsT[kq * 4 + 2][row] = v.z;
        xsT[kq * 4 + 3][row] = v.w;
      }
    }
    // stage W tile
    {
      constexpr int CQ = N / 4;        // float4 cols per k-row
      constexpr int KP = 256 / CQ;     // k rows per pass
      int cq = tid & (CQ - 1);
      int kk = tid / CQ;
#pragma unroll
      for (int p = 0; p < KC / KP; ++p) {
        int k = kk + p * KP;
        *reinterpret_cast<float4*>(&Ws[k][cq * 4]) =
            *reinterpret_cast<const float4*>(&W[(size_t)(kb + k) * N + cq * 4]);
      }
    }
    __syncthreads();

#pragma unroll 8
    for (int k = 0; k < KC; ++k) {
      float a[8], b[TN];
      float4 va0 = *reinterpret_cast<const float4*>(&xsT[k][r0]);
      float4 va1 = *reinterpret_cast<const float4*>(&xsT[k][r0 + 4]);
      a[0] = va0.x; a[1] = va0.y; a[2] = va0.z; a[3] = va0.w;
      a[4] = va1.x; a[5] = va1.y; a[6] = va1.z; a[7] = va1.w;
      float4 vb0 = *reinterpret_cast<const float4*>(&Ws[k][c0]);
      b[0] = vb0.x; b[1] = vb0.y; b[2] = vb0.z; b[3] = vb0.w;
      if (TN == 8) {
        float4 vb1 = *reinterpret_cast<const float4*>(&Ws[k][c0 + 4]);
        b[4] = vb1.x; b[5] = vb1.y; b[6] = vb1.z; b[7] = vb1.w;
      }
#pragma unroll
      for (int i = 0; i < 8; ++i)
#pragma unroll
        for (int j = 0; j < TN; ++j) acc[i][j] = fmaf(a[i], b[j], acc[i][j]);
    }
    __syncthreads();
  }

  // epilogue: scale by dinv[row], store
#pragma unroll
  for (int i = 0; i < 8; ++i) {
    int grow = rowbase + r0 + i;
    if (grow < M) {
      float dv = dinv[grow];
#pragma unroll
      for (int j = 0; j < TN; j += 4) {
        float4 v = make_float4(acc[i][j] * dv, acc[i][j + 1] * dv,
                               acc[i][j + 2] * dv, acc[i][j + 3] * dv);
        *reinterpret_cast<float4*>(&out[(size_t)grow * N + c0 + j]) = v;
      }
    }
  }
}

// ---------------- Aggregation: out[i] = f(dinv[i]*(hs[i] + sum_{j->i} hs[j]) + b)
// MODE 0: ReLU   MODE 1: log_softmax over D (D must be 64)
template <int D, int MODE>
__global__ __launch_bounds__(256) void k_agg(
    const float* __restrict__ hs, const float* __restrict__ dinv,
    const int* __restrict__ rowptr, const int* __restrict__ csr,
    const float* __restrict__ bias, float* __restrict__ out, int n) {
  constexpr int VEC = D / 64;  // 2 for D=128, 1 for D=64
  int lane = threadIdx.x & 63;
  int node = blockIdx.x * 4 + (threadIdx.x >> 6);
  if (node >= n) return;
  int beg = rowptr[node], end = rowptr[node + 1];

  float acc0, acc1 = 0.f;
  if (VEC == 2) {
    float2 v = *reinterpret_cast<const float2*>(&hs[(size_t)node * D + lane * 2]);
    acc0 = v.x; acc1 = v.y;
  } else {
    acc0 = hs[(size_t)node * D + lane];
  }

  int e = beg;
  for (; e + 4 <= end; e += 4) {
    int s0 = csr[e], s1 = csr[e + 1], s2 = csr[e + 2], s3 = csr[e + 3];
    if (VEC == 2) {
      float2 v0 = *reinterpret_cast<const float2*>(&hs[(size_t)s0 * D + lane * 2]);
      float2 v1 = *reinterpret_cast<const float2*>(&hs[(size_t)s1 * D + lane * 2]);
      float2 v2 = *reinterpret_cast<const float2*>(&hs[(size_t)s2 * D + lane * 2]);
      float2 v3 = *reinterpret_cast<const float2*>(&hs[(size_t)s3 * D + lane * 2]);
      acc0 += v0.x + v1.x + v2.x + v3.x;
      acc1 += v0.y + v1.y + v2.y + v3.y;
    } else {
      acc0 += hs[(size_t)s0 * D + lane] + hs[(size_t)s1 * D + lane] +
              hs[(size_t)s2 * D + lane] + hs[(size_t)s3 * D + lane];
    }
  }
  for (; e < end; ++e) {
    int s = csr[e];
    if (VEC == 2) {
      float2 v = *reinterpret_cast<const float2*>(&hs[(size_t)s * D + lane * 2]);
      acc0 += v.x; acc1 += v.y;
    } else {
      acc0 += hs[(size_t)s * D + lane];
    }
  }

  float dv = dinv[node];
  if (MODE == 0) {
    if (VEC == 2) {
      float o0 = fmaxf(dv * acc0 + bias[lane * 2 + 0], 0.f);
      float o1 = fmaxf(dv * acc1 + bias[lane * 2 + 1], 0.f);
      float2 o = make_float2(o0, o1);
      *reinterpret_cast<float2*>(&out[(size_t)node * D + lane * 2]) = o;
    } else {
      out[(size_t)node * D + lane] = fmaxf(dv * acc0 + bias[lane], 0.f);
    }
  } else {
    // D == 64, VEC == 1: fused log_softmax over the 64 lanes
    float val = dv * acc0 + bias[lane];
    float m = val;
#pragma unroll
    for (int o = 32; o > 0; o >>= 1) m = fmaxf(m, __shfl_xor(m, o));
    float ex = expf(val - m);
    float ssum = ex;
#pragma unroll
    for (int o = 32; o > 0; o >>= 1) ssum += __shfl_xor(ssum, o);
    out[(size_t)node * D + lane] = val - m - logf(ssum);
  }
}

// ---------------- launch ----------------
extern "C" void kernel_launch(void* const* d_in, const int* in_sizes, int n_in,
                              void* d_out, int out_size, void* d_ws, size_t ws_size,
                              hipStream_t stream) {
  const float* x  = (const float*)d_in[0];
  const float* W1 = (const float*)d_in[1];
  const float* b1 = (const float*)d_in[2];
  const float* W2 = (const float*)d_in[3];
  const float* b2 = (const float*)d_in[4];
  const float* W3 = (const float*)d_in[5];
  const float* b3 = (const float*)d_in[6];
  const int*   ei = (const int*)d_in[7];

  int n = in_sizes[0] / N_IN;
  int E = in_sizes[7] / 2;
  const int* src = ei;
  const int* dst = ei + E;

  char* w = (char*)d_ws;
  size_t off = 0;
  auto alloc = [&](size_t bytes) -> void* {
    void* p = w + off;
    off = (off + bytes + 255) & ~(size_t)255;
    return p;
  };
  float* bufA = (float*)alloc((size_t)n * N_HID * sizeof(float));
  float* bufB = (float*)alloc((size_t)n * N_HID * sizeof(float));
  float* dinv = (float*)alloc((size_t)n * sizeof(float));
  int* cntfill = (int*)alloc((size_t)2 * n * sizeof(int));
  int* cnt = cntfill;
  int* fill = cntfill + n;
  int* rowptr = (int*)alloc((size_t)(n + 1) * sizeof(int));
  int* csr = (int*)alloc((size_t)E * sizeof(int));
  int* bsum = (int*)alloc(4096);

  // ---- CSR by dst (+ degrees, dinv) ----
  k_zero_int<<<(2 * n + 255) / 256, 256, 0, stream>>>(cnt, 2 * n);
  k_hist<<<1024, 256, 0, stream>>>(dst, E, cnt);
  int nb = (n + SCAN_CHUNK - 1) / SCAN_CHUNK;
  k_block_sums<<<nb, SCAN_CHUNK, 0, stream>>>(cnt, n, bsum);
  k_scan_bsums<<<1, 64, 0, stream>>>(bsum, nb);
  k_scan_final<<<nb, SCAN_CHUNK, 0, stream>>>(cnt, n, bsum, rowptr, dinv, E);
  k_fill<<<1024, 256, 0, stream>>>(src, dst, E, rowptr, fill, csr);

  int gb = (n + 127) / 128;
  int ab = (n + 3) / 4;
  // ---- layer 1 ----
  k_gemm_scale<N_HID><<<gb, 256, 0, stream>>>(x, W1, dinv, bufA, n);
  k_agg<N_HID, 0><<<ab, 256, 0, stream>>>(bufA, dinv, rowptr, csr, b1, bufB, n);
  // ---- layer 2 ----
  k_gemm_scale<N_HID><<<gb, 256, 0, stream>>>(bufB, W2, dinv, bufA, n);
  k_agg<N_HID, 0><<<ab, 256, 0, stream>>>(bufA, dinv, rowptr, csr, b2, bufB, n);
  // ---- layer 3 (+ fused log_softmax) ----
  k_gemm_scale<N_OUT><<<gb, 256, 0, stream>>>(bufB, W3, dinv, bufA, n);
  k_agg<N_OUT, 1><<<ab, 256, 0, stream>>>(bufA, dinv, rowptr, csr, b3, (float*)d_out, n);
}

// Round 2
// 230.075 us; speedup vs baseline: 1.3150x; 1.3150x over previous
//
#include <hip/hip_runtime.h>
#include <math.h>

#define N_IN  128
#define N_HID 128
#define N_OUT 64

typedef _Float16 f16x8 __attribute__((ext_vector_type(8)));
typedef _Float16 f16x2 __attribute__((ext_vector_type(2)));
typedef float f32x4 __attribute__((ext_vector_type(4)));

// ---------------- CSR build ----------------
__global__ void k_zero_int(int* __restrict__ p, int n) {
  int i = blockIdx.x * blockDim.x + threadIdx.x;
  if (i < n) p[i] = 0;
}

__global__ void k_hist(const int* __restrict__ dst, int E, int* __restrict__ cnt) {
  int stride = gridDim.x * blockDim.x;
  for (int i = blockIdx.x * blockDim.x + threadIdx.x; i < E; i += stride)
    atomicAdd(&cnt[dst[i]], 1);
}

#define SCAN_CHUNK 512

__global__ __launch_bounds__(SCAN_CHUNK) void k_block_sums(
    const int* __restrict__ cnt, int n, int* __restrict__ bsum) {
  __shared__ int s[SCAN_CHUNK];
  int i = blockIdx.x * SCAN_CHUNK + threadIdx.x;
  s[threadIdx.x] = (i < n) ? cnt[i] : 0;
  __syncthreads();
  for (int off = SCAN_CHUNK / 2; off > 0; off >>= 1) {
    if (threadIdx.x < off) s[threadIdx.x] += s[threadIdx.x + off];
    __syncthreads();
  }
  if (threadIdx.x == 0) bsum[blockIdx.x] = s[0];
}

__global__ void k_scan_bsums(int* __restrict__ bsum, int nb) {
  if (blockIdx.x == 0 && threadIdx.x == 0) {
    int acc = 0;
    for (int i = 0; i < nb; ++i) { int v = bsum[i]; bsum[i] = acc; acc += v; }
  }
}

__global__ __launch_bounds__(SCAN_CHUNK) void k_scan_final(
    const int* __restrict__ cnt, int n, const int* __restrict__ bsum,
    int* __restrict__ rowptr, float* __restrict__ dinv, int E) {
  __shared__ int s[SCAN_CHUNK];
  int i = blockIdx.x * SCAN_CHUNK + threadIdx.x;
  int v = (i < n) ? cnt[i] : 0;
  s[threadIdx.x] = v;
  __syncthreads();
  for (int off = 1; off < SCAN_CHUNK; off <<= 1) {
    int t = (threadIdx.x >= off) ? s[threadIdx.x - off] : 0;
    __syncthreads();
    s[threadIdx.x] += t;
    __syncthreads();
  }
  if (i < n) {
    rowptr[i] = bsum[blockIdx.x] + s[threadIdx.x] - v;  // exclusive
    dinv[i] = rsqrtf((float)v + 1.0f);                   // +1 self loop
    if (i == n - 1) rowptr[n] = E;
  }
}

__global__ void k_fill(const int* __restrict__ src, const int* __restrict__ dst, int E,
                       const int* __restrict__ rowptr, int* __restrict__ fill,
                       int* __restrict__ csr) {
  int stride = gridDim.x * blockDim.x;
  for (int i = blockIdx.x * blockDim.x + threadIdx.x; i < E; i += stride) {
    int d = dst[i];
    int pos = rowptr[d] + atomicAdd(&fill[d], 1);
    csr[pos] = src[i];
  }
}

// ---------------- W fragment pack: W fp32 [K][N] -> fp16 frag-ordered ----------------
// frag element j of lane l, k-step s, n-tile t is W[s*32 + (l>>4)*8 + j][t*16 + (l&15)]
__global__ void k_pack_w(const float* __restrict__ W, _Float16* __restrict__ Wp,
                         int N, int K) {
  int idx = blockIdx.x * blockDim.x + threadIdx.x;
  int total = (N / 16) * (K / 32) * 64;
  if (idx >= total) return;
  int l = idx & 63;
  int ts = idx >> 6;
  int KS = K / 32;
  int t = ts / KS, s = ts - t * KS;
  int col = t * 16 + (l & 15);
  int k0 = s * 32 + (l >> 4) * 8;
  f16x8 f;
#pragma unroll
  for (int j = 0; j < 8; ++j) f[j] = (_Float16)W[(size_t)(k0 + j) * N + col];
  *reinterpret_cast<f16x8*>(&Wp[(size_t)idx * 8]) = f;
}

// ---------------- MFMA GEMM (+ dinv row scale), out fp16 ----------------
// out[r][c] = dinv[r] * sum_k A[r][k] * W[k][c];  K = 128 fixed
template <int N, bool AFP32>
__global__ __launch_bounds__(256) void k_gemm_mfma(
    const void* __restrict__ Av, const _Float16* __restrict__ Wp,
    const float* __restrict__ dinv, _Float16* __restrict__ out, int M) {
  constexpr int K = 128, KS = K / 32, NT = N / 16;
  int lane = threadIdx.x & 63;
  int wave = threadIdx.x >> 6;
  int rowbase = blockIdx.x * 64 + wave * 16;
  int arow = rowbase + (lane & 15);
  int arc = arow < M ? arow : M - 1;  // clamp (stores are guarded)
  int k0 = (lane >> 4) * 8;

  f16x8 afrag[KS];
  if (AFP32) {
    const float* A = (const float*)Av;
#pragma unroll
    for (int s = 0; s < KS; ++s) {
      float4 v0 = *reinterpret_cast<const float4*>(&A[(size_t)arc * K + s * 32 + k0]);
      float4 v1 = *reinterpret_cast<const float4*>(&A[(size_t)arc * K + s * 32 + k0 + 4]);
      f16x8 f;
      f[0] = (_Float16)v0.x; f[1] = (_Float16)v0.y;
      f[2] = (_Float16)v0.z; f[3] = (_Float16)v0.w;
      f[4] = (_Float16)v1.x; f[5] = (_Float16)v1.y;
      f[6] = (_Float16)v1.z; f[7] = (_Float16)v1.w;
      afrag[s] = f;
    }
  } else {
    const _Float16* A = (const _Float16*)Av;
#pragma unroll
    for (int s = 0; s < KS; ++s)
      afrag[s] = *reinterpret_cast<const f16x8*>(&A[(size_t)arc * K + s * 32 + k0]);
  }

  f32x4 acc[NT] = {};
#pragma unroll
  for (int t = 0; t < NT; ++t)
#pragma unroll
    for (int s = 0; s < KS; ++s) {
      f16x8 b = *reinterpret_cast<const f16x8*>(&Wp[((size_t)(t * KS + s) * 64 + lane) * 8]);
      acc[t] = __builtin_amdgcn_mfma_f32_16x16x32_f16(afrag[s], b, acc[t], 0, 0, 0);
    }

  // C/D layout: col = lane&15, row = (lane>>4)*4 + r   [m89]
  int crow = (lane >> 4) * 4;
  int col = lane & 15;
#pragma unroll
  for (int r = 0; r < 4; ++r) {
    int grow = rowbase + crow + r;
    if (grow < M) {
      float dv = dinv[grow];
#pragma unroll
      for (int t = 0; t < NT; ++t)
        out[(size_t)grow * N + t * 16 + col] = (_Float16)(acc[t][r] * dv);
    }
  }
}

// ---------------- Aggregation (fp16 table, fp32 accum) ----------------
// out[i] = f(dinv[i]*(hs[i] + sum_{j->i} hs[j]) + b)
// MODE 0: ReLU, out fp16    MODE 1: log_softmax (D==64), out fp32
template <int D, int MODE>
__global__ __launch_bounds__(256) void k_agg16(
    const _Float16* __restrict__ hs, const float* __restrict__ dinv,
    const int* __restrict__ rowptr, const int* __restrict__ csr,
    const float* __restrict__ bias, void* __restrict__ outv, int n) {
  constexpr int VEC = D / 64;  // 2 for D=128, 1 for D=64
  int lane = threadIdx.x & 63;
  int node = blockIdx.x * 4 + (threadIdx.x >> 6);
  if (node >= n) return;
  int beg = rowptr[node], end = rowptr[node + 1];

  float acc0, acc1 = 0.f;
  if (VEC == 2) {
    f16x2 v = *reinterpret_cast<const f16x2*>(&hs[(size_t)node * D + lane * 2]);
    acc0 = (float)v[0]; acc1 = (float)v[1];
  } else {
    acc0 = (float)hs[(size_t)node * D + lane];
  }

  int e = beg;
  for (; e + 8 <= end; e += 8) {
    int si[8];
#pragma unroll
    for (int j = 0; j < 8; ++j) si[j] = csr[e + j];
    if (VEC == 2) {
      f16x2 vv[8];
#pragma unroll
      for (int j = 0; j < 8; ++j)
        vv[j] = *reinterpret_cast<const f16x2*>(&hs[(size_t)si[j] * D + lane * 2]);
#pragma unroll
      for (int j = 0; j < 8; ++j) { acc0 += (float)vv[j][0]; acc1 += (float)vv[j][1]; }
    } else {
      _Float16 vv[8];
#pragma unroll
      for (int j = 0; j < 8; ++j) vv[j] = hs[(size_t)si[j] * D + lane];
#pragma unroll
      for (int j = 0; j < 8; ++j) acc0 += (float)vv[j];
    }
  }
  for (; e < end; ++e) {
    int s = csr[e];
    if (VEC == 2) {
      f16x2 v = *reinterpret_cast<const f16x2*>(&hs[(size_t)s * D + lane * 2]);
      acc0 += (float)v[0]; acc1 += (float)v[1];
    } else {
      acc0 += (float)hs[(size_t)s * D + lane];
    }
  }

  float dv = dinv[node];
  if (MODE == 0) {
    _Float16* out = (_Float16*)outv;
    if (VEC == 2) {
      float o0 = fmaxf(dv * acc0 + bias[lane * 2 + 0], 0.f);
      float o1 = fmaxf(dv * acc1 + bias[lane * 2 + 1], 0.f);
      f16x2 o; o[0] = (_Float16)o0; o[1] = (_Float16)o1;
      *reinterpret_cast<f16x2*>(&out[(size_t)node * D + lane * 2]) = o;
    } else {
      out[(size_t)node * D + lane] = (_Float16)fmaxf(dv * acc0 + bias[lane], 0.f);
    }
  } else {
    float* out = (float*)outv;
    float val = dv * acc0 + bias[lane];
    float m = val;
#pragma unroll
    for (int o = 32; o > 0; o >>= 1) m = fmaxf(m, __shfl_xor(m, o));
    float ex = expf(val - m);
    float ssum = ex;
#pragma unroll
    for (int o = 32; o > 0; o >>= 1) ssum += __shfl_xor(ssum, o);
    out[(size_t)node * D + lane] = val - m - logf(ssum);
  }
}

// ---------------- launch ----------------
extern "C" void kernel_launch(void* const* d_in, const int* in_sizes, int n_in,
                              void* d_out, int out_size, void* d_ws, size_t ws_size,
                              hipStream_t stream) {
  const float* x  = (const float*)d_in[0];
  const float* W1 = (const float*)d_in[1];
  const float* b1 = (const float*)d_in[2];
  const float* W2 = (const float*)d_in[3];
  const float* b2 = (const float*)d_in[4];
  const float* W3 = (const float*)d_in[5];
  const float* b3 = (const float*)d_in[6];
  const int*   ei = (const int*)d_in[7];

  int n = in_sizes[0] / N_IN;
  int E = in_sizes[7] / 2;
  const int* src = ei;
  const int* dst = ei + E;

  char* w = (char*)d_ws;
  size_t off = 0;
  auto alloc = [&](size_t bytes) -> void* {
    void* p = w + off;
    off = (off + bytes + 255) & ~(size_t)255;
    return p;
  };
  _Float16* hsA = (_Float16*)alloc((size_t)n * N_HID * sizeof(_Float16));
  _Float16* hB  = (_Float16*)alloc((size_t)n * N_HID * sizeof(_Float16));
  _Float16* Wp1 = (_Float16*)alloc((size_t)N_IN * N_HID * sizeof(_Float16));
  _Float16* Wp2 = (_Float16*)alloc((size_t)N_HID * N_HID * sizeof(_Float16));
  _Float16* Wp3 = (_Float16*)alloc((size_t)N_HID * N_OUT * sizeof(_Float16));
  float* dinv = (float*)alloc((size_t)n * sizeof(float));
  int* cntfill = (int*)alloc((size_t)2 * n * sizeof(int));
  int* cnt = cntfill;
  int* fill = cntfill + n;
  int* rowptr = (int*)alloc((size_t)(n + 1) * sizeof(int));
  int* csr = (int*)alloc((size_t)E * sizeof(int));
  int* bsum = (int*)alloc(4096);

  // ---- CSR by dst (+ degrees, dinv) ----
  k_zero_int<<<(2 * n + 255) / 256, 256, 0, stream>>>(cnt, 2 * n);
  k_hist<<<1024, 256, 0, stream>>>(dst, E, cnt);
  int nb = (n + SCAN_CHUNK - 1) / SCAN_CHUNK;
  k_block_sums<<<nb, SCAN_CHUNK, 0, stream>>>(cnt, n, bsum);
  k_scan_bsums<<<1, 64, 0, stream>>>(bsum, nb);
  k_scan_final<<<nb, SCAN_CHUNK, 0, stream>>>(cnt, n, bsum, rowptr, dinv, E);
  k_fill<<<1024, 256, 0, stream>>>(src, dst, E, rowptr, fill, csr);

  // ---- pack weights to fp16 fragment order ----
  {
    int t1 = (N_HID / 16) * (N_IN / 32) * 64;
    k_pack_w<<<(t1 + 255) / 256, 256, 0, stream>>>(W1, Wp1, N_HID, N_IN);
    int t2 = (N_HID / 16) * (N_HID / 32) * 64;
    k_pack_w<<<(t2 + 255) / 256, 256, 0, stream>>>(W2, Wp2, N_HID, N_HID);
    int t3 = (N_OUT / 16) * (N_HID / 32) * 64;
    k_pack_w<<<(t3 + 255) / 256, 256, 0, stream>>>(W3, Wp3, N_OUT, N_HID);
  }

  int gb = (n + 63) / 64;
  int ab = (n + 3) / 4;
  // ---- layer 1 ----
  k_gemm_mfma<N_HID, true><<<gb, 256, 0, stream>>>(x, Wp1, dinv, hsA, n);
  k_agg16<N_HID, 0><<<ab, 256, 0, stream>>>(hsA, dinv, rowptr, csr, b1, hB, n);
  // ---- layer 2 ----
  k_gemm_mfma<N_HID, false><<<gb, 256, 0, stream>>>(hB, Wp2, dinv, hsA, n);
  k_agg16<N_HID, 0><<<ab, 256, 0, stream>>>(hsA, dinv, rowptr, csr, b2, hB, n);
  // ---- layer 3 (+ fused log_softmax) ----
  k_gemm_mfma<N_OUT, false><<<gb, 256, 0, stream>>>(hB, Wp3, dinv, hsA, n);
  k_agg16<N_OUT, 1><<<ab, 256, 0, stream>>>(hsA, dinv, rowptr, csr, b3, d_out, n);
}

// Round 3
// 217.728 us; speedup vs baseline: 1.3896x; 1.0567x over previous
//
#include <hip/hip_runtime.h>
#include <math.h>

#define N_IN  128
#define N_HID 128
#define N_OUT 64

typedef _Float16 f16x8 __attribute__((ext_vector_type(8)));
typedef _Float16 f16x4 __attribute__((ext_vector_type(4)));
typedef _Float16 f16x2 __attribute__((ext_vector_type(2)));
typedef float f32x4 __attribute__((ext_vector_type(4)));

// ---------------- CSR build ----------------
__global__ void k_zero_int(int* __restrict__ p, int n) {
  int i = blockIdx.x * blockDim.x + threadIdx.x;
  if (i < n) p[i] = 0;
}

__global__ void k_hist(const int* __restrict__ dst, int E, int* __restrict__ cnt) {
  int i0 = (blockIdx.x * blockDim.x + threadIdx.x) * 4;
  int stride = gridDim.x * blockDim.x * 4;
  for (; i0 + 4 <= E; i0 += stride) {
    int4 d = *reinterpret_cast<const int4*>(&dst[i0]);
    atomicAdd(&cnt[d.x], 1);
    atomicAdd(&cnt[d.y], 1);
    atomicAdd(&cnt[d.z], 1);
    atomicAdd(&cnt[d.w], 1);
  }
  if (i0 < E)
    for (; i0 < E; ++i0) atomicAdd(&cnt[dst[i0]], 1);
}

#define SCAN_CHUNK 512

__global__ __launch_bounds__(SCAN_CHUNK) void k_block_sums(
    const int* __restrict__ cnt, int n, int* __restrict__ bsum) {
  __shared__ int s[SCAN_CHUNK];
  int i = blockIdx.x * SCAN_CHUNK + threadIdx.x;
  s[threadIdx.x] = (i < n) ? cnt[i] : 0;
  __syncthreads();
  for (int off = SCAN_CHUNK / 2; off > 0; off >>= 1) {
    if (threadIdx.x < off) s[threadIdx.x] += s[threadIdx.x + off];
    __syncthreads();
  }
  if (threadIdx.x == 0) bsum[blockIdx.x] = s[0];
}

__global__ __launch_bounds__(128) void k_scan_bsums(int* __restrict__ bsum, int nb) {
  __shared__ int s[128];
  int t = threadIdx.x;
  if (nb <= 128) {
    int v = (t < nb) ? bsum[t] : 0;
    s[t] = v;
    __syncthreads();
    for (int off = 1; off < 128; off <<= 1) {
      int u = (t >= off) ? s[t - off] : 0;
      __syncthreads();
      s[t] += u;
      __syncthreads();
    }
    if (t < nb) bsum[t] = s[t] - v;  // exclusive
  } else if (t == 0) {
    int acc = 0;
    for (int i = 0; i < nb; ++i) { int v = bsum[i]; bsum[i] = acc; acc += v; }
  }
}

__global__ __launch_bounds__(SCAN_CHUNK) void k_scan_final(
    const int* __restrict__ cnt, int n, const int* __restrict__ bsum,
    int* __restrict__ rowptr, float* __restrict__ dinv, int E) {
  __shared__ int s[SCAN_CHUNK];
  int i = blockIdx.x * SCAN_CHUNK + threadIdx.x;
  int v = (i < n) ? cnt[i] : 0;
  s[threadIdx.x] = v;
  __syncthreads();
  for (int off = 1; off < SCAN_CHUNK; off <<= 1) {
    int t = (threadIdx.x >= off) ? s[threadIdx.x - off] : 0;
    __syncthreads();
    s[threadIdx.x] += t;
    __syncthreads();
  }
  if (i < n) {
    rowptr[i] = bsum[blockIdx.x] + s[threadIdx.x] - v;  // exclusive
    dinv[i] = rsqrtf((float)v + 1.0f);                   // +1 self loop
    if (i == n - 1) rowptr[n] = E;
  }
}

// fill CSR; consumes cnt via atomicSub (cnt ends at zero)
__global__ void k_fill(const int* __restrict__ src, const int* __restrict__ dst, int E,
                       const int* __restrict__ rowptr, int* __restrict__ cnt,
                       int* __restrict__ csr) {
  int i0 = (blockIdx.x * blockDim.x + threadIdx.x) * 4;
  int stride = gridDim.x * blockDim.x * 4;
  for (; i0 + 4 <= E; i0 += stride) {
    int4 d = *reinterpret_cast<const int4*>(&dst[i0]);
    int4 sr = *reinterpret_cast<const int4*>(&src[i0]);
    csr[rowptr[d.x] + atomicSub(&cnt[d.x], 1) - 1] = sr.x;
    csr[rowptr[d.y] + atomicSub(&cnt[d.y], 1) - 1] = sr.y;
    csr[rowptr[d.z] + atomicSub(&cnt[d.z], 1) - 1] = sr.z;
    csr[rowptr[d.w] + atomicSub(&cnt[d.w], 1) - 1] = sr.w;
  }
  if (i0 < E)
    for (; i0 < E; ++i0) {
      int d = dst[i0];
      csr[rowptr[d] + atomicSub(&cnt[d], 1) - 1] = src[i0];
    }
}

// ---------------- W fragment pack (all three weights in one kernel) ----------------
// frag element j of lane l, k-step s, n-tile t is W[s*32 + (l>>4)*8 + j][t*16 + (l&15)]
__device__ inline void pack_one(const float* __restrict__ W, _Float16* __restrict__ Wp,
                                int N, int K, int idx) {
  int l = idx & 63;
  int ts = idx >> 6;
  int KS = K / 32;
  int t = ts / KS, s = ts - t * KS;
  int col = t * 16 + (l & 15);
  int k0 = s * 32 + (l >> 4) * 8;
  f16x8 f;
#pragma unroll
  for (int j = 0; j < 8; ++j) f[j] = (_Float16)W[(size_t)(k0 + j) * N + col];
  *reinterpret_cast<f16x8*>(&Wp[(size_t)idx * 8]) = f;
}

__global__ void k_pack_all(const float* __restrict__ W1, const float* __restrict__ W2,
                           const float* __restrict__ W3, _Float16* __restrict__ Wp1,
                           _Float16* __restrict__ Wp2, _Float16* __restrict__ Wp3) {
  // t1 = (128/16)*(128/32)*64 = 2048, t2 = 2048, t3 = (64/16)*(128/32)*64 = 1024
  int idx = blockIdx.x * blockDim.x + threadIdx.x;
  if (idx < 2048) pack_one(W1, Wp1, N_HID, N_IN, idx);
  else if (idx < 4096) pack_one(W2, Wp2, N_HID, N_HID, idx - 2048);
  else if (idx < 5120) pack_one(W3, Wp3, N_OUT, N_HID, idx - 4096);
}

// ---------------- MFMA GEMM (+ dinv row scale), out fp16 ----------------
template <int N, bool AFP32>
__global__ __launch_bounds__(256) void k_gemm_mfma(
    const void* __restrict__ Av, const _Float16* __restrict__ Wp,
    const float* __restrict__ dinv, _Float16* __restrict__ out, int M) {
  constexpr int K = 128, KS = K / 32, NT = N / 16;
  int lane = threadIdx.x & 63;
  int wave = threadIdx.x >> 6;
  int rowbase = blockIdx.x * 64 + wave * 16;
  int arow = rowbase + (lane & 15);
  int arc = arow < M ? arow : M - 1;  // clamp (stores are guarded)
  int k0 = (lane >> 4) * 8;

  f16x8 afrag[KS];
  if (AFP32) {
    const float* A = (const float*)Av;
#pragma unroll
    for (int s = 0; s < KS; ++s) {
      float4 v0 = *reinterpret_cast<const float4*>(&A[(size_t)arc * K + s * 32 + k0]);
      float4 v1 = *reinterpret_cast<const float4*>(&A[(size_t)arc * K + s * 32 + k0 + 4]);
      f16x8 f;
      f[0] = (_Float16)v0.x; f[1] = (_Float16)v0.y;
      f[2] = (_Float16)v0.z; f[3] = (_Float16)v0.w;
      f[4] = (_Float16)v1.x; f[5] = (_Float16)v1.y;
      f[6] = (_Float16)v1.z; f[7] = (_Float16)v1.w;
      afrag[s] = f;
    }
  } else {
    const _Float16* A = (const _Float16*)Av;
#pragma unroll
    for (int s = 0; s < KS; ++s)
      afrag[s] = *reinterpret_cast<const f16x8*>(&A[(size_t)arc * K + s * 32 + k0]);
  }

  f32x4 acc[NT] = {};
#pragma unroll
  for (int t = 0; t < NT; ++t)
#pragma unroll
    for (int s = 0; s < KS; ++s) {
      f16x8 b = *reinterpret_cast<const f16x8*>(&Wp[((size_t)(t * KS + s) * 64 + lane) * 8]);
      acc[t] = __builtin_amdgcn_mfma_f32_16x16x32_f16(afrag[s], b, acc[t], 0, 0, 0);
    }

  // C/D layout: col = lane&15, row = (lane>>4)*4 + r
  int crow = (lane >> 4) * 4;
  int col = lane & 15;
#pragma unroll
  for (int r = 0; r < 4; ++r) {
    int grow = rowbase + crow + r;
    if (grow < M) {
      float dv = dinv[grow];
#pragma unroll
      for (int t = 0; t < NT; ++t)
        out[(size_t)grow * N + t * 16 + col] = (_Float16)(acc[t][r] * dv);
    }
  }
}

// ---------------- Aggregation D=128: wave/node, 2 edges in flight (half-waves) ----------------
// out[i] = relu(dinv[i]*(hs[i] + sum_{j->i} hs[j]) + b), fp16 out
__global__ __launch_bounds__(256) void k_agg128(
    const _Float16* __restrict__ hs, const float* __restrict__ dinv,
    const int* __restrict__ rowptr, const int* __restrict__ csr,
    const float* __restrict__ bias, _Float16* __restrict__ out, int n) {
  constexpr int D = 128;
  int lane = threadIdx.x & 63;
  int node = blockIdx.x * 4 + (threadIdx.x >> 6);
  if (node >= n) return;
  int h = lane >> 5;   // half
  int j = lane & 31;   // covers dims [j*4, j*4+4)
  int beg = rowptr[node], end = rowptr[node + 1];

  float acc[4] = {0.f, 0.f, 0.f, 0.f};
  if (h == 0) {  // self term (once)
    f16x4 v = *reinterpret_cast<const f16x4*>(&hs[(size_t)node * D + j * 4]);
#pragma unroll
    for (int k = 0; k < 4; ++k) acc[k] = (float)v[k];
  }

  int e = beg;
  for (; e + 16 <= end; e += 16) {
    int idx[8];
#pragma unroll
    for (int it = 0; it < 8; ++it) idx[it] = csr[e + 2 * it + h];
    f16x4 v[8];
#pragma unroll
    for (int it = 0; it < 8; ++it)
      v[it] = *reinterpret_cast<const f16x4*>(&hs[(size_t)idx[it] * D + j * 4]);
#pragma unroll
    for (int it = 0; it < 8; ++it)
#pragma unroll
      for (int k = 0; k < 4; ++k) acc[k] += (float)v[it][k];
  }
  for (; e + 2 <= end; e += 2) {
    int s = csr[e + h];
    f16x4 v = *reinterpret_cast<const f16x4*>(&hs[(size_t)s * D + j * 4]);
#pragma unroll
    for (int k = 0; k < 4; ++k) acc[k] += (float)v[k];
  }
  if (e < end && h == 0) {  // single leftover edge
    int s = csr[e];
    f16x4 v = *reinterpret_cast<const f16x4*>(&hs[(size_t)s * D + j * 4]);
#pragma unroll
    for (int k = 0; k < 4; ++k) acc[k] += (float)v[k];
  }

  // combine halves
#pragma unroll
  for (int k = 0; k < 4; ++k) acc[k] += __shfl_xor(acc[k], 32);

  float dv = dinv[node];
  // half h writes dims j*4 + h*2 + {0,1}
  int d0 = j * 4 + h * 2;
  float o0 = fmaxf(dv * acc[h * 2 + 0] + bias[d0 + 0], 0.f);
  float o1 = fmaxf(dv * acc[h * 2 + 1] + bias[d0 + 1], 0.f);
  f16x2 o; o[0] = (_Float16)o0; o[1] = (_Float16)o1;
  *reinterpret_cast<f16x2*>(&out[(size_t)node * D + d0]) = o;
}

// ---------------- Aggregation D=64 + log_softmax: wave/node, 4 edges in flight ----------------
__global__ __launch_bounds__(256) void k_agg64_lsm(
    const _Float16* __restrict__ hs, const float* __restrict__ dinv,
    const int* __restrict__ rowptr, const int* __restrict__ csr,
    const float* __restrict__ bias, float* __restrict__ out, int n) {
  constexpr int D = 64;
  int lane = threadIdx.x & 63;
  int node = blockIdx.x * 4 + (threadIdx.x >> 6);
  if (node >= n) return;
  int q = lane >> 4;   // quarter
  int j = lane & 15;   // covers dims [j*4, j*4+4)
  int beg = rowptr[node], end = rowptr[node + 1];

  float acc[4] = {0.f, 0.f, 0.f, 0.f};
  if (q == 0) {  // self term
    f16x4 v = *reinterpret_cast<const f16x4*>(&hs[(size_t)node * D + j * 4]);
#pragma unroll
    for (int k = 0; k < 4; ++k) acc[k] = (float)v[k];
  }

  int e = beg;
  for (; e + 16 <= end; e += 16) {
    int idx[4];
#pragma unroll
    for (int it = 0; it < 4; ++it) idx[it] = csr[e + 4 * it + q];
    f16x4 v[4];
#pragma unroll
    for (int it = 0; it < 4; ++it)
      v[it] = *reinterpret_cast<const f16x4*>(&hs[(size_t)idx[it] * D + j * 4]);
#pragma unroll
    for (int it = 0; it < 4; ++it)
#pragma unroll
      for (int k = 0; k < 4; ++k) acc[k] += (float)v[it][k];
  }
  for (; e + 4 <= end; e += 4) {
    int s = csr[e + q];
    f16x4 v = *reinterpret_cast<const f16x4*>(&hs[(size_t)s * D + j * 4]);
#pragma unroll
    for (int k = 0; k < 4; ++k) acc[k] += (float)v[k];
  }
  {
    int r = end - e;  // 0..3
    if (q < r) {
      int s = csr[e + q];
      f16x4 v = *reinterpret_cast<const f16x4*>(&hs[(size_t)s * D + j * 4]);
#pragma unroll
      for (int k = 0; k < 4; ++k) acc[k] += (float)v[k];
    }
  }

  // combine quarters
#pragma unroll
  for (int k = 0; k < 4; ++k) {
    acc[k] += __shfl_xor(acc[k], 16);
    acc[k] += __shfl_xor(acc[k], 32);
  }

  float dv = dinv[node];
  float val[4];
#pragma unroll
  for (int k = 0; k < 4; ++k) val[k] = dv * acc[k] + bias[j * 4 + k];

  // log_softmax over 64 dims: values replicated across quarters, reduce within 16-lane group
  float m = fmaxf(fmaxf(val[0], val[1]), fmaxf(val[2], val[3]));
#pragma unroll
  for (int o = 8; o > 0; o >>= 1) m = fmaxf(m, __shfl_xor(m, o));
  float ssum = 0.f;
#pragma unroll
  for (int k = 0; k < 4; ++k) ssum += expf(val[k] - m);
#pragma unroll
  for (int o = 8; o > 0; o >>= 1) ssum += __shfl_xor(ssum, o);
  float lse = m + logf(ssum);

  if (q == 0) {
    float4 o = make_float4(val[0] - lse, val[1] - lse, val[2] - lse, val[3] - lse);
    *reinterpret_cast<float4*>(&out[(size_t)node * D + j * 4]) = o;
  }
}

// ---------------- launch ----------------
extern "C" void kernel_launch(void* const* d_in, const int* in_sizes, int n_in,
                              void* d_out, int out_size, void* d_ws, size_t ws_size,
                              hipStream_t stream) {
  const float* x  = (const float*)d_in[0];
  const float* W1 = (const float*)d_in[1];
  const float* b1 = (const float*)d_in[2];
  const float* W2 = (const float*)d_in[3];
  const float* b2 = (const float*)d_in[4];
  const float* W3 = (const float*)d_in[5];
  const float* b3 = (const float*)d_in[6];
  const int*   ei = (const int*)d_in[7];

  int n = in_sizes[0] / N_IN;
  int E = in_sizes[7] / 2;
  const int* src = ei;
  const int* dst = ei + E;

  char* w = (char*)d_ws;
  size_t off = 0;
  auto alloc = [&](size_t bytes) -> void* {
    void* p = w + off;
    off = (off + bytes + 255) & ~(size_t)255;
    return p;
  };
  _Float16* hsA = (_Float16*)alloc((size_t)n * N_HID * sizeof(_Float16));
  _Float16* hB  = (_Float16*)alloc((size_t)n * N_HID * sizeof(_Float16));
  _Float16* Wp1 = (_Float16*)alloc((size_t)N_IN * N_HID * sizeof(_Float16));
  _Float16* Wp2 = (_Float16*)alloc((size_t)N_HID * N_HID * sizeof(_Float16));
  _Float16* Wp3 = (_Float16*)alloc((size_t)N_HID * N_OUT * sizeof(_Float16));
  float* dinv = (float*)alloc((size_t)n * sizeof(float));
  int* cnt = (int*)alloc((size_t)n * sizeof(int));
  int* rowptr = (int*)alloc((size_t)(n + 1) * sizeof(int));
  int* csr = (int*)alloc((size_t)E * sizeof(int));
  int* bsum = (int*)alloc(4096);

  // ---- CSR by dst (+ degrees, dinv) ----
  k_zero_int<<<(n + 255) / 256, 256, 0, stream>>>(cnt, n);
  {
    int blocks = min((E / 4 + 255) / 256, 1024);
    k_hist<<<blocks, 256, 0, stream>>>(dst, E, cnt);
    int nb = (n + SCAN_CHUNK - 1) / SCAN_CHUNK;
    k_block_sums<<<nb, SCAN_CHUNK, 0, stream>>>(cnt, n, bsum);
    k_scan_bsums<<<1, 128, 0, stream>>>(bsum, nb);
    k_scan_final<<<nb, SCAN_CHUNK, 0, stream>>>(cnt, n, bsum, rowptr, dinv, E);
    k_fill<<<blocks, 256, 0, stream>>>(src, dst, E, rowptr, cnt, csr);
  }

  // ---- pack weights to fp16 fragment order ----
  k_pack_all<<<20, 256, 0, stream>>>(W1, W2, W3, Wp1, Wp2, Wp3);

  int gb = (n + 63) / 64;
  int ab = (n + 3) / 4;
  // ---- layer 1 ----
  k_gemm_mfma<N_HID, true><<<gb, 256, 0, stream>>>(x, Wp1, dinv, hsA, n);
  k_agg128<<<ab, 256, 0, stream>>>(hsA, dinv, rowptr, csr, b1, hB, n);
  // ---- layer 2 ----
  k_gemm_mfma<N_HID, false><<<gb, 256, 0, stream>>>(hB, Wp2, dinv, hsA, n);
  k_agg128<<<ab, 256, 0, stream>>>(hsA, dinv, rowptr, csr, b2, hB, n);
  // ---- layer 3 (+ fused log_softmax) ----
  k_gemm_mfma<N_OUT, false><<<gb, 256, 0, stream>>>(hB, Wp3, dinv, hsA, n);
  k_agg64_lsm<<<ab, 256, 0, stream>>>(hsA, dinv, rowptr, csr, b3, (float*)d_out, n);
}